// Round 8
// baseline (284.176 us; speedup 1.0000x reference)
//
#include <hip/hip_runtime.h>
#include <hip/hip_bf16.h>

// (B,T,C,H) = (4,2048,1024,16), D=64
#define Bb 4
#define Tt 2048
#define Cc 1024
#define Hh 16

typedef unsigned short u16;
typedef __attribute__((ext_vector_type(8))) __bf16 bf16x8;
typedef __attribute__((ext_vector_type(4))) float  f32x4;

__device__ __forceinline__ u16 f2bf_hw(float f) {         // native cvt on gfx950
    __bf16 h = (__bf16)f;
    return *(u16*)&h;
}

// v_cvt_pk_bf16_f32: low16 = bf16(a), high16 = bf16(b)
__device__ __forceinline__ unsigned cvt_pk_bf16(float a, float b) {
    unsigned r;
    asm("v_cvt_pk_bf16_f32 %0, %1, %2" : "=v"(r) : "v"(a), "v"(b));
    return r;
}

__device__ __forceinline__ float fexp2(float x) {
#if __has_builtin(__builtin_amdgcn_exp2f)
    return __builtin_amdgcn_exp2f(x);
#else
    return __expf(x * 0.6931471805599453f);
#endif
}

__device__ __forceinline__ void gld_lds16(const void* g, void* l) {
    __builtin_amdgcn_global_load_lds(
        (__attribute__((address_space(1))) void*)(g),
        (__attribute__((address_space(3))) void*)(l),
        16, 0, 0);
}

__device__ __forceinline__ f32x4 mfma16(bf16x8 a, bf16x8 b, f32x4 c) {
    return __builtin_amdgcn_mfma_f32_16x16x32_bf16(a, b, c, 0, 0, 0);
}

// ---------------------------------------------------------------------------
__global__ void cast_f32_bf16(const float* __restrict__ in, u16* __restrict__ out, int n4) {
    int i = blockIdx.x * 256 + threadIdx.x;
    if (i < n4) {
        float4 v = ((const float4*)in)[i];
        uint2 o;
        o.x = cvt_pk_bf16(v.x, v.y);
        o.y = cvt_pk_bf16(v.z, v.w);
        ((uint2*)out)[i] = o;
    }
}

// cast + transpose: in [K,N] f32 -> out [N,K] bf16, rows n < scaleN scaled by sv.
__global__ void castT_f32_bf16(const float* __restrict__ in, u16* __restrict__ out,
                               int K, int N, int scaleN, float sv) {
    __shared__ float Ls[64][65];
    const int n0 = blockIdx.x * 64, k0 = blockIdx.y * 64;
    const int t = threadIdx.x;
    #pragma unroll
    for (int s = 0; s < 4; ++s) {
        int idx = t + 256 * s;
        int r   = idx >> 4;
        int c4  = (idx & 15) * 4;
        float4 v = *(const float4*)&in[(size_t)(k0 + r) * N + n0 + c4];
        Ls[r][c4 + 0] = v.x; Ls[r][c4 + 1] = v.y;
        Ls[r][c4 + 2] = v.z; Ls[r][c4 + 3] = v.w;
    }
    __syncthreads();
    #pragma unroll
    for (int s = 0; s < 2; ++s) {
        int idx = t + 256 * s;
        int n   = idx >> 3;
        int kc  = (idx & 7) * 8;
        const float sc = (n0 + n < scaleN) ? sv : 1.0f;
        alignas(16) u16 tmp[8];
        #pragma unroll
        for (int i = 0; i < 8; ++i) tmp[i] = f2bf_hw(Ls[kc + i][n] * sc);
        *(uint4*)&out[(size_t)(n0 + n) * K + k0 + kc] = *(const uint4*)tmp;
    }
}

// ---------------------------------------------------------------------------
// Repack K and V slices of qkv into MFMA-fragment order (unchanged).
// ---------------------------------------------------------------------------
__global__ void repack_frags(const u16* __restrict__ qkv,
                             u16* __restrict__ kx, u16* __restrict__ vx) {
    __shared__ u16 Kt[64 * 80];
    __shared__ u16 Vt[64 * 80];
    const int t = threadIdx.x;
    const int ch = blockIdx.x, bh = blockIdx.y, b = bh >> 4, h = bh & 15;
    const int kc = ch * 64;

    #pragma unroll
    for (int u = 0; u < 2; ++u) {
        int id = t + 256 * u;                  // 0..511
        int key = id >> 3, c8 = id & 7;
        const size_t row = (size_t)(b * Tt + kc + key) * (3 * Cc) + h * 64 + c8 * 8;
        *(uint4*)&Kt[key * 80 + c8 * 8] = *(const uint4*)&qkv[row + Cc];
        *(uint4*)&Vt[key * 80 + c8 * 8] = *(const uint4*)&qkv[row + 2 * Cc];
    }
    __syncthreads();

    const size_t obase = (size_t)(bh * 32 + ch) * 4096;
    #pragma unroll
    for (int u = 0; u < 2; ++u) {
        int id = t + 256 * u;                  // 0..511
        int lane = id & 63, ks = (id >> 6) & 1, jt = id >> 7;
        int l16 = lane & 15, quad = lane >> 4;
        uint4 kv = *(const uint4*)&Kt[(16 * jt + l16) * 80 + 32 * ks + quad * 8];
        *(uint4*)&kx[obase + (size_t)(jt * 2 + ks) * 512 + lane * 8] = kv;
        alignas(16) u16 tmp[8];
        #pragma unroll
        for (int j = 0; j < 8; ++j)
            tmp[j] = Vt[(32 * ks + quad * 8 + j) * 80 + 16 * jt + l16];
        *(uint4*)&vx[obase + (size_t)(jt * 2 + ks) * 512 + lane * 8] = *(const uint4*)tmp;
    }
}

// ---------------------------------------------------------------------------
// bf16 GEMM, B^T input (m97 structure). gemm1 + gemm2. See round-5 note:
// 128^2 beats 256^2 here on grid residency (1536 blocks @3/CU vs 384 @1/CU).
// ---------------------------------------------------------------------------
__global__ __launch_bounds__(256, 3) void gemm_bt_bf16(
    const u16* __restrict__ A, const u16* __restrict__ Bt,
    const float* __restrict__ bias,
    u16* __restrict__ outB, float* __restrict__ outF,
    int M, int N, int K)
{
    __shared__ u16 As[128 * 32];
    __shared__ u16 Bs[128 * 32];
    const int t = threadIdx.x;
    const int w = t >> 6, lane = t & 63;
    const int quad = lane >> 4, l16 = lane & 15;
    const int wr = w >> 1, wc = w & 1;
    const int m0 = blockIdx.y * 128, n0 = blockIdx.x * 128;

    int aoff[4], boff[4];
    #pragma unroll
    for (int i = 0; i < 4; ++i) {
        int rA = 64 * wr + 16 * i + l16;
        aoff[i] = rA * 32 + ((quad ^ ((rA >> 1) & 3)) * 8);
        int rB = 64 * wc + 16 * i + l16;
        boff[i] = rB * 32 + ((quad ^ ((rB >> 1) & 3)) * 8);
    }

    f32x4 acc[4][4] = {};

    for (int k0 = 0; k0 < K; k0 += 32) {
        __syncthreads();
        #pragma unroll
        for (int u = 0; u < 2; ++u) {
            const int i   = 2 * w + u;
            const int row = 16 * i + (lane >> 2);
            const int c   = (lane & 3) ^ ((row >> 1) & 3);
            gld_lds16(A  + (size_t)(m0 + row) * K + k0 + c * 8, (void*)(As + i * 512 + lane * 8));
            gld_lds16(Bt + (size_t)(n0 + row) * K + k0 + c * 8, (void*)(Bs + i * 512 + lane * 8));
        }
        asm volatile("s_waitcnt vmcnt(0)" ::: "memory");
        __syncthreads();

        bf16x8 af[4], bfr[4];
        #pragma unroll
        for (int i = 0; i < 4; ++i) af[i]  = *(const bf16x8*)&As[aoff[i]];
        #pragma unroll
        for (int j = 0; j < 4; ++j) bfr[j] = *(const bf16x8*)&Bs[boff[j]];
        #pragma unroll
        for (int i = 0; i < 4; ++i)
            #pragma unroll
            for (int j = 0; j < 4; ++j)
                acc[i][j] = mfma16(af[i], bfr[j], acc[i][j]);
    }

    const int rbase = m0 + 64 * wr + quad * 4;
    const int cbase = n0 + 64 * wc + l16;
    if (outF) {
        float bv[4];
        #pragma unroll
        for (int j = 0; j < 4; ++j) bv[j] = bias[cbase + 16 * j];
        #pragma unroll
        for (int i = 0; i < 4; ++i)
            #pragma unroll
            for (int r = 0; r < 4; ++r) {
                size_t ro = (size_t)(rbase + 16 * i + r) * N;
                #pragma unroll
                for (int j = 0; j < 4; ++j)
                    outF[ro + cbase + 16 * j] = acc[i][j][r] + bv[j];
            }
    } else {
        #pragma unroll
        for (int i = 0; i < 4; ++i)
            #pragma unroll
            for (int r = 0; r < 4; ++r) {
                size_t ro = (size_t)(rbase + 16 * i + r) * N;
                #pragma unroll
                for (int j = 0; j < 4; ++j)
                    outB[ro + cbase + 16 * j] = f2bf_hw(acc[i][j][r]);
            }
    }
}

// ---------------------------------------------------------------------------
// Flash attention, 4-wave blocks, QBLK=32 per wave (128 q-rows/block).
// Round-7 post-mortem: LDS shrink to 24.5KB did NOT raise occupancy because
// the 512-block grid caps residency at 2 blocks/CU — the grid, not LDS, was
// binding. Fix: halve per-wave q-rows -> grid 64x16 = 1024 blocks -> 4
// blocks/CU (LDS allows 6), 16 waves/CU = 2x TLP. Round-4's QBLK=32
// regression was private per-wave K/V re-reads (FETCH 31.8MB); K/V is now
// block-shared in LDS so FETCH stays ~21MB (kx/vx L2-resident per XCD,
// id%8 = bh%8 keeps all q-blocks of a bh on one XCD). K/V L2-side read
// doubles (~512MB ~ 15us at L2 BW) — hidden under compute.
// Structure per chunk: T14 reg-prefetch next chunk -> K/V frags from LDS
// (linear ds_read_b128, conflict-free) -> per q-tile S/exp/P-slab/PV ->
// barrier -> ds_write prefetched chunk -> barrier.
// ---------------------------------------------------------------------------
__global__ __launch_bounds__(256, 2) void attn_mfma4(
    const u16* __restrict__ qkv, const u16* __restrict__ kx, const u16* __restrict__ vx,
    const int* __restrict__ mask, u16* __restrict__ outO)
{
    __shared__ u16 KVs[8192];          // K:0..4095 | V:4096..8191  (16KB)
    __shared__ u16 Pss[4][16 * 68];    // per-wave per-qq P slab    (8.5KB)

    const int t = threadIdx.x;
    const int w = t >> 6, lane = t & 63;
    const int quad = lane >> 4, l16 = lane & 15;
    const int bh = blockIdx.x, qb = blockIdx.y, b = bh >> 4, h = bh & 15;

    // ---- valid length L from prefix mask ----
    int sum = 0;
    {
        const int4* mp = (const int4*)(mask + b * Tt) + lane * 8;
        #pragma unroll
        for (int i = 0; i < 8; ++i) { int4 m4 = mp[i]; sum += m4.x + m4.y + m4.z + m4.w; }
        #pragma unroll
        for (int off = 1; off < 64; off <<= 1) sum += __shfl_xor(sum, off);
    }
    const int L = sum;

    // ---- persistent Q fragments (pre-scaled at weight cast) ----
    const int q0 = qb * 128 + w * 32;
    bf16x8 qf[2][2];
    #pragma unroll
    for (int qq = 0; qq < 2; ++qq) {
        const u16* qp = qkv + (size_t)(b * Tt + q0 + 16 * qq + l16) * (3 * Cc) + h * 64 + quad * 8;
        qf[qq][0] = *(const bf16x8*)(qp);
        qf[qq][1] = *(const bf16x8*)(qp + 32);
    }

    f32x4 oacc[2][4] = {};
    f32x4 lacc[2]    = {};
    const __bf16 onebf = (__bf16)1.0f;
    const bf16x8 ones  = {onebf, onebf, onebf, onebf, onebf, onebf, onebf, onebf};

    const int nfull = L >> 6;
    const int nch   = (L + 63) >> 6;
    const size_t cb0 = (size_t)bh * 32 * 4096;   // chunk stride 4096 u16
    u16* Pw = Pss[w];

    // ---- prologue: chunk 0 -> regs -> LDS ----
    {
        uint4 k0a = *(const uint4*)&kx[cb0 + t * 8];
        uint4 k0b = *(const uint4*)&kx[cb0 + 2048 + t * 8];
        uint4 v0a = *(const uint4*)&vx[cb0 + t * 8];
        uint4 v0b = *(const uint4*)&vx[cb0 + 2048 + t * 8];
        *(uint4*)&KVs[t * 8]        = k0a;
        *(uint4*)&KVs[2048 + t * 8] = k0b;
        *(uint4*)&KVs[4096 + t * 8] = v0a;
        *(uint4*)&KVs[6144 + t * 8] = v0b;
    }
    __syncthreads();

    for (int ch = 0; ch < nch; ++ch) {
        // ---- T14: issue next-chunk loads now; first use is after barrier ----
        const int cc = (ch + 1 < nch) ? ch + 1 : ch;
        const size_t nb = cb0 + (size_t)cc * 4096;
        uint4 nk0 = *(const uint4*)&kx[nb + t * 8];
        uint4 nk1 = *(const uint4*)&kx[nb + 2048 + t * 8];
        uint4 nv0 = *(const uint4*)&vx[nb + t * 8];
        uint4 nv1 = *(const uint4*)&vx[nb + 2048 + t * 8];

        const u16* Kb = KVs;
        const u16* Vb = KVs + 4096;

        // ---- K fragments from LDS (linear, conflict-free) ----
        bf16x8 kf[4][2];
        #pragma unroll
        for (int jt = 0; jt < 4; ++jt)
            #pragma unroll
            for (int ks = 0; ks < 2; ++ks)
                kf[jt][ks] = *(const bf16x8*)&Kb[(jt * 2 + ks) * 512 + lane * 8];

        // ---- V fragments ----
        bf16x8 vf[4][2];
        #pragma unroll
        for (int dt = 0; dt < 4; ++dt)
            #pragma unroll
            for (int ks = 0; ks < 2; ++ks)
                vf[dt][ks] = *(const bf16x8*)&Vb[(dt * 2 + ks) * 512 + lane * 8];

        // ---- per q-tile: S, exp, P slab roundtrip, PV ----
        #pragma unroll
        for (int qq = 0; qq < 2; ++qq) {
            f32x4 st[4];
            #pragma unroll
            for (int jt = 0; jt < 4; ++jt) {
                f32x4 z = {0.f, 0.f, 0.f, 0.f};
                z = mfma16(kf[jt][0], qf[qq][0], z);
                st[jt] = mfma16(kf[jt][1], qf[qq][1], z);
            }
            uint2 pk[4];
            if (ch < nfull) {
                #pragma unroll
                for (int jt = 0; jt < 4; ++jt) {
                    pk[jt].x = cvt_pk_bf16(fexp2(st[jt][0]), fexp2(st[jt][1]));
                    pk[jt].y = cvt_pk_bf16(fexp2(st[jt][2]), fexp2(st[jt][3]));
                }
            } else {
                const int kc = ch * 64;
                #pragma unroll
                for (int jt = 0; jt < 4; ++jt) {
                    const int kb = kc + 16 * jt + quad * 4;
                    float e[4];
                    #pragma unroll
                    for (int r = 0; r < 4; ++r)
                        e[r] = (kb + r < L) ? fexp2(st[jt][r]) : 0.f;
                    pk[jt].x = cvt_pk_bf16(e[0], e[1]);
                    pk[jt].y = cvt_pk_bf16(e[2], e[3]);
                }
            }
            #pragma unroll
            for (int jt = 0; jt < 4; ++jt)
                *(uint2*)&Pw[l16 * 68 + 16 * jt + quad * 4] = pk[jt];

            #pragma unroll
            for (int ks = 0; ks < 2; ++ks) {
                const u16* pr = &Pw[l16 * 68 + 32 * ks + quad * 8];
                uint2 pa = *(const uint2*)pr;
                uint2 pb = *(const uint2*)(pr + 4);
                uint4 comb = {pa.x, pa.y, pb.x, pb.y};
                bf16x8 pf = *(const bf16x8*)&comb;
                #pragma unroll
                for (int dt = 0; dt < 4; ++dt)
                    oacc[qq][dt] = mfma16(pf, vf[dt][ks], oacc[qq][dt]);
                lacc[qq] = mfma16(pf, ones, lacc[qq]);
            }
        }

        // ---- rotate buffer: all readers done -> write next chunk ----
        __syncthreads();
        *(uint4*)&KVs[t * 8]        = nk0;
        *(uint4*)&KVs[2048 + t * 8] = nk1;
        *(uint4*)&KVs[4096 + t * 8] = nv0;
        *(uint4*)&KVs[6144 + t * 8] = nv1;
        __syncthreads();
    }

    // ---- write O (bf16, [B*T, C]) ----
    #pragma unroll
    for (int qq = 0; qq < 2; ++qq)
        #pragma unroll
        for (int r = 0; r < 4; ++r) {
            const float inv = 1.f / lacc[qq][r];
            const size_t ro = (size_t)(b * Tt + q0 + 16 * qq + quad * 4 + r) * Cc + h * 64 + l16;
            #pragma unroll
            for (int dt = 0; dt < 4; ++dt)
                outO[ro + 16 * dt] = f2bf_hw(oacc[qq][dt][r] * inv);
        }
}

// ---------------------------------------------------------------------------
extern "C" void kernel_launch(void* const* d_in, const int* in_sizes, int n_in,
                              void* d_out, int out_size, void* d_ws, size_t ws_size,
                              hipStream_t stream) {
    const float* x     = (const float*)d_in[0];
    const int*   mask  = (const int*)  d_in[1];
    const float* w_qkv = (const float*)d_in[2];
    const float* w_out = (const float*)d_in[3];
    const float* b_out = (const float*)d_in[4];
    float*       outp  = (float*)d_out;

    const int M = Bb * Tt;                        // 8192
    char* ws = (char*)d_ws;
    u16* xb     = (u16*)(ws);                     // 16 MB  [M,C]  (dead after gemm1)
    u16* wqkvT  = (u16*)(ws + (16u << 20));       //  6 MB  [3C,C]
    u16* woutT  = (u16*)(ws + (22u << 20));       //  2 MB  [C,C]
    u16* qkv    = (u16*)(ws + (24u << 20));       // 48 MB  [M,3C]
    u16* kx     = (u16*)(ws + (72u << 20));       // 16 MB  frag-packed K
    u16* vx     = (u16*)(ws + (88u << 20));       // 16 MB  frag-packed V^T
    u16* attnO  = (u16*)(ws);                     // 16 MB  reuses xb region

    const float c2 = 0.18033688011112042f;        // 0.125 * log2(e), folded into Q weights

    cast_f32_bf16<<<(M * Cc / 4 + 255) / 256, 256, 0, stream>>>(x, xb, M * Cc / 4);
    castT_f32_bf16<<<dim3(3 * Cc / 64, Cc / 64), 256, 0, stream>>>(w_qkv, wqkvT, Cc, 3 * Cc, Cc, c2);
    castT_f32_bf16<<<dim3(Cc / 64, Cc / 64), 256, 0, stream>>>(w_out, woutT, Cc, Cc, 0, 1.0f);

    gemm_bt_bf16<<<dim3(3 * Cc / 128, M / 128), 256, 0, stream>>>(
        xb, wqkvT, nullptr, qkv, nullptr, M, 3 * Cc, Cc);

    repack_frags<<<dim3(Tt / 64, Bb * Hh), 256, 0, stream>>>(qkv, kx, vx);

    // attn: 4-wave blocks, QBLK=32/wave, 128 q-rows/block, 1024 blocks
    attn_mfma4<<<dim3(Bb * Hh, Tt / 128), 256, 0, stream>>>(qkv, kx, vx, mask, attnO);

    gemm_bt_bf16<<<dim3(Cc / 128, M / 128), 256, 0, stream>>>(
        attnO, woutT, b_out, nullptr, outp, M, Cc, Cc);
}

// Round 9
// 260.883 us; speedup vs baseline: 1.0893x; 1.0893x over previous
//
#include <hip/hip_runtime.h>
#include <hip/hip_bf16.h>

// (B,T,C,H) = (4,2048,1024,16), D=64
#define Bb 4
#define Tt 2048
#define Cc 1024
#define Hh 16

typedef unsigned short u16;
typedef __attribute__((ext_vector_type(8))) __bf16 bf16x8;
typedef __attribute__((ext_vector_type(4))) float  f32x4;

__device__ __forceinline__ u16 f2bf_hw(float f) {         // native cvt on gfx950
    __bf16 h = (__bf16)f;
    return *(u16*)&h;
}

// v_cvt_pk_bf16_f32: low16 = bf16(a), high16 = bf16(b)
__device__ __forceinline__ unsigned cvt_pk_bf16(float a, float b) {
    unsigned r;
    asm("v_cvt_pk_bf16_f32 %0, %1, %2" : "=v"(r) : "v"(a), "v"(b));
    return r;
}

__device__ __forceinline__ float fexp2(float x) {
#if __has_builtin(__builtin_amdgcn_exp2f)
    return __builtin_amdgcn_exp2f(x);
#else
    return __expf(x * 0.6931471805599453f);
#endif
}

__device__ __forceinline__ void gld_lds16(const void* g, void* l) {
    __builtin_amdgcn_global_load_lds(
        (__attribute__((address_space(1))) void*)(g),
        (__attribute__((address_space(3))) void*)(l),
        16, 0, 0);
}

__device__ __forceinline__ f32x4 mfma16(bf16x8 a, bf16x8 b, f32x4 c) {
    return __builtin_amdgcn_mfma_f32_16x16x32_bf16(a, b, c, 0, 0, 0);
}

// ---------------------------------------------------------------------------
__global__ void cast_f32_bf16(const float* __restrict__ in, u16* __restrict__ out, int n4) {
    int i = blockIdx.x * 256 + threadIdx.x;
    if (i < n4) {
        float4 v = ((const float4*)in)[i];
        uint2 o;
        o.x = cvt_pk_bf16(v.x, v.y);
        o.y = cvt_pk_bf16(v.z, v.w);
        ((uint2*)out)[i] = o;
    }
}

// cast + transpose: in [K,N] f32 -> out [N,K] bf16, rows n < scaleN scaled by sv.
__global__ void castT_f32_bf16(const float* __restrict__ in, u16* __restrict__ out,
                               int K, int N, int scaleN, float sv) {
    __shared__ float Ls[64][65];
    const int n0 = blockIdx.x * 64, k0 = blockIdx.y * 64;
    const int t = threadIdx.x;
    #pragma unroll
    for (int s = 0; s < 4; ++s) {
        int idx = t + 256 * s;
        int r   = idx >> 4;
        int c4  = (idx & 15) * 4;
        float4 v = *(const float4*)&in[(size_t)(k0 + r) * N + n0 + c4];
        Ls[r][c4 + 0] = v.x; Ls[r][c4 + 1] = v.y;
        Ls[r][c4 + 2] = v.z; Ls[r][c4 + 3] = v.w;
    }
    __syncthreads();
    #pragma unroll
    for (int s = 0; s < 2; ++s) {
        int idx = t + 256 * s;
        int n   = idx >> 3;
        int kc  = (idx & 7) * 8;
        const float sc = (n0 + n < scaleN) ? sv : 1.0f;
        alignas(16) u16 tmp[8];
        #pragma unroll
        for (int i = 0; i < 8; ++i) tmp[i] = f2bf_hw(Ls[kc + i][n] * sc);
        *(uint4*)&out[(size_t)(n0 + n) * K + k0 + kc] = *(const uint4*)tmp;
    }
}

// ---------------------------------------------------------------------------
// bf16 GEMM, B^T input (m97 structure) — gemm2 (out-proj) only.
// ---------------------------------------------------------------------------
__global__ __launch_bounds__(256, 3) void gemm_bt_bf16(
    const u16* __restrict__ A, const u16* __restrict__ Bt,
    const float* __restrict__ bias,
    u16* __restrict__ outB, float* __restrict__ outF,
    int M, int N, int K)
{
    __shared__ u16 As[128 * 32];
    __shared__ u16 Bs[128 * 32];
    const int t = threadIdx.x;
    const int w = t >> 6, lane = t & 63;
    const int quad = lane >> 4, l16 = lane & 15;
    const int wr = w >> 1, wc = w & 1;
    const int m0 = blockIdx.y * 128, n0 = blockIdx.x * 128;

    int aoff[4], boff[4];
    #pragma unroll
    for (int i = 0; i < 4; ++i) {
        int rA = 64 * wr + 16 * i + l16;
        aoff[i] = rA * 32 + ((quad ^ ((rA >> 1) & 3)) * 8);
        int rB = 64 * wc + 16 * i + l16;
        boff[i] = rB * 32 + ((quad ^ ((rB >> 1) & 3)) * 8);
    }

    f32x4 acc[4][4] = {};

    for (int k0 = 0; k0 < K; k0 += 32) {
        __syncthreads();
        #pragma unroll
        for (int u = 0; u < 2; ++u) {
            const int i   = 2 * w + u;
            const int row = 16 * i + (lane >> 2);
            const int c   = (lane & 3) ^ ((row >> 1) & 3);
            gld_lds16(A  + (size_t)(m0 + row) * K + k0 + c * 8, (void*)(As + i * 512 + lane * 8));
            gld_lds16(Bt + (size_t)(n0 + row) * K + k0 + c * 8, (void*)(Bs + i * 512 + lane * 8));
        }
        asm volatile("s_waitcnt vmcnt(0)" ::: "memory");
        __syncthreads();

        bf16x8 af[4], bfr[4];
        #pragma unroll
        for (int i = 0; i < 4; ++i) af[i]  = *(const bf16x8*)&As[aoff[i]];
        #pragma unroll
        for (int j = 0; j < 4; ++j) bfr[j] = *(const bf16x8*)&Bs[boff[j]];
        #pragma unroll
        for (int i = 0; i < 4; ++i)
            #pragma unroll
            for (int j = 0; j < 4; ++j)
                acc[i][j] = mfma16(af[i], bfr[j], acc[i][j]);
    }

    const int rbase = m0 + 64 * wr + quad * 4;
    const int cbase = n0 + 64 * wc + l16;
    if (outF) {
        float bv[4];
        #pragma unroll
        for (int j = 0; j < 4; ++j) bv[j] = bias[cbase + 16 * j];
        #pragma unroll
        for (int i = 0; i < 4; ++i)
            #pragma unroll
            for (int r = 0; r < 4; ++r) {
                size_t ro = (size_t)(rbase + 16 * i + r) * N;
                #pragma unroll
                for (int j = 0; j < 4; ++j)
                    outF[ro + cbase + 16 * j] = acc[i][j][r] + bv[j];
            }
    } else {
        #pragma unroll
        for (int i = 0; i < 4; ++i)
            #pragma unroll
            for (int r = 0; r < 4; ++r) {
                size_t ro = (size_t)(rbase + 16 * i + r) * N;
                #pragma unroll
                for (int j = 0; j < 4; ++j)
                    outB[ro + cbase + 16 * j] = f2bf_hw(acc[i][j][r]);
            }
    }
}

// ---------------------------------------------------------------------------
// gemm1 with FUSED repack: same 128^2 m97-structure main loop, but the
// epilogue scatters directly into the attn-consumable layouts, eliminating
// the repack_frags pass (~96MB of traffic + one launch).
//   cols [0,1024):    Q  -> qb[row*Cc + col]                (compact [M,C])
//   cols [1024,2048): K  -> kx fragment layout
//   cols [2048,3072): V  -> vx fragment layout
// Fragment indices are SEPARABLE: idx = rowpart(row) + colpart(col)
//   K: row -> b,ch,jt,sl (rowK = b*2097152 + ch*4096 + jt*1024 + sl*8)
//      col -> h,ks,q8,j  (colK = h*131072 + ks*512 + q8*128 + j)
//   V: row -> b,ch,ks,q8,j (rowV = b*2097152 + ch*4096 + ks*512 + q8*128 + j)
//      col -> h,jt,sl      (colV = h*131072 + jt*1024 + sl*8)
// (verified element-wise against repack_frags for K[100][29], V[37][50], ...)
// Region is uniform per block (blockIdx.x>>3) -> no per-element branching.
// ---------------------------------------------------------------------------
__global__ __launch_bounds__(256, 3) void gemm_qkv_bt(
    const u16* __restrict__ A, const u16* __restrict__ Bt,
    u16* __restrict__ outQ, u16* __restrict__ kx, u16* __restrict__ vx)
{
    const int M = Bb * Tt, N = 3 * Cc, K = Cc;
    __shared__ u16 As[128 * 32];
    __shared__ u16 Bs[128 * 32];
    const int t = threadIdx.x;
    const int w = t >> 6, lane = t & 63;
    const int quad = lane >> 4, l16 = lane & 15;
    const int wr = w >> 1, wc = w & 1;
    const int m0 = blockIdx.y * 128, n0 = blockIdx.x * 128;
    (void)M; (void)N;

    int aoff[4], boff[4];
    #pragma unroll
    for (int i = 0; i < 4; ++i) {
        int rA = 64 * wr + 16 * i + l16;
        aoff[i] = rA * 32 + ((quad ^ ((rA >> 1) & 3)) * 8);
        int rB = 64 * wc + 16 * i + l16;
        boff[i] = rB * 32 + ((quad ^ ((rB >> 1) & 3)) * 8);
    }

    f32x4 acc[4][4] = {};

    for (int k0 = 0; k0 < K; k0 += 32) {
        __syncthreads();
        #pragma unroll
        for (int u = 0; u < 2; ++u) {
            const int i   = 2 * w + u;
            const int row = 16 * i + (lane >> 2);
            const int c   = (lane & 3) ^ ((row >> 1) & 3);
            gld_lds16(A  + (size_t)(m0 + row) * K + k0 + c * 8, (void*)(As + i * 512 + lane * 8));
            gld_lds16(Bt + (size_t)(n0 + row) * K + k0 + c * 8, (void*)(Bs + i * 512 + lane * 8));
        }
        asm volatile("s_waitcnt vmcnt(0)" ::: "memory");
        __syncthreads();

        bf16x8 af[4], bfr[4];
        #pragma unroll
        for (int i = 0; i < 4; ++i) af[i]  = *(const bf16x8*)&As[aoff[i]];
        #pragma unroll
        for (int j = 0; j < 4; ++j) bfr[j] = *(const bf16x8*)&Bs[boff[j]];
        #pragma unroll
        for (int i = 0; i < 4; ++i)
            #pragma unroll
            for (int j = 0; j < 4; ++j)
                acc[i][j] = mfma16(af[i], bfr[j], acc[i][j]);
    }

    const int rbase = m0 + 64 * wr + quad * 4;      // + 16*i + r = global row
    const int cbase = n0 + 64 * wc + l16;           // + 16*j    = global col
    const int region = n0 >> 10;                    // 0=Q, 1=K, 2=V (uniform)

    if (region == 0) {
        #pragma unroll
        for (int i = 0; i < 4; ++i)
            #pragma unroll
            for (int r = 0; r < 4; ++r) {
                size_t ro = (size_t)(rbase + 16 * i + r) * Cc;
                #pragma unroll
                for (int j = 0; j < 4; ++j)
                    outQ[ro + cbase + 16 * j] = f2bf_hw(acc[i][j][r]);
            }
    } else if (region == 1) {
        int colK[4];
        #pragma unroll
        for (int j = 0; j < 4; ++j) {
            const int c = (cbase - 1024) + 16 * j;
            const int h = c >> 6, d = c & 63;
            colK[j] = h * 131072 + (d >> 5) * 512 + ((d >> 3) & 3) * 128 + (d & 7);
        }
        #pragma unroll
        for (int i = 0; i < 4; ++i)
            #pragma unroll
            for (int r = 0; r < 4; ++r) {
                const int row = rbase + 16 * i + r;
                const int b = row >> 11, key = row & 2047;
                const int ch = key >> 6, keyr = key & 63;
                const int rowK = b * 2097152 + ch * 4096 + (keyr >> 4) * 1024 + (keyr & 15) * 8;
                #pragma unroll
                for (int j = 0; j < 4; ++j)
                    kx[rowK + colK[j]] = f2bf_hw(acc[i][j][r]);
            }
    } else {
        int colV[4];
        #pragma unroll
        for (int j = 0; j < 4; ++j) {
            const int c = (cbase - 2048) + 16 * j;
            const int h = c >> 6, d = c & 63;
            colV[j] = h * 131072 + (d >> 4) * 1024 + (d & 15) * 8;
        }
        #pragma unroll
        for (int i = 0; i < 4; ++i)
            #pragma unroll
            for (int r = 0; r < 4; ++r) {
                const int row = rbase + 16 * i + r;
                const int b = row >> 11, key = row & 2047;
                const int ch = key >> 6, keyr = key & 63;
                const int rowV = b * 2097152 + ch * 4096 + (keyr >> 5) * 512
                               + ((keyr >> 3) & 3) * 128 + (keyr & 7);
                #pragma unroll
                for (int j = 0; j < 4; ++j)
                    vx[rowV + colV[j]] = f2bf_hw(acc[i][j][r]);
            }
    }
}

// ---------------------------------------------------------------------------
// Flash attention — round-7 best config (74.8us), reverted after round-8's
// QBLK=32 regression (85.3us: occupancy counter never moved across 5 configs;
// stop chasing TLP). 4 waves/block, QBLK=64/wave, 256 q-rows/block, 512
// blocks. Single-buffered KV (16KB) + T14 reg prefetch; per-wave 16x68 P
// slab. Q now read from compact qb [M,C] (repack fused into gemm1).
// ---------------------------------------------------------------------------
__global__ __launch_bounds__(256, 2) void attn_mfma4(
    const u16* __restrict__ qb, const u16* __restrict__ kx, const u16* __restrict__ vx,
    const int* __restrict__ mask, u16* __restrict__ outO)
{
    __shared__ u16 KVs[8192];          // K:0..4095 | V:4096..8191  (16KB)
    __shared__ u16 Pss[4][16 * 68];    // per-wave per-qq P slab    (8.5KB)

    const int t = threadIdx.x;
    const int w = t >> 6, lane = t & 63;
    const int quad = lane >> 4, l16 = lane & 15;
    const int bh = blockIdx.x, qblk = blockIdx.y, b = bh >> 4, h = bh & 15;

    // ---- valid length L from prefix mask ----
    int sum = 0;
    {
        const int4* mp = (const int4*)(mask + b * Tt) + lane * 8;
        #pragma unroll
        for (int i = 0; i < 8; ++i) { int4 m4 = mp[i]; sum += m4.x + m4.y + m4.z + m4.w; }
        #pragma unroll
        for (int off = 1; off < 64; off <<= 1) sum += __shfl_xor(sum, off);
    }
    const int L = sum;

    // ---- persistent Q fragments (pre-scaled at weight cast) ----
    const int q0 = qblk * 256 + w * 64;
    bf16x8 qf[4][2];
    #pragma unroll
    for (int qq = 0; qq < 4; ++qq) {
        const u16* qp = qb + (size_t)(b * Tt + q0 + 16 * qq + l16) * Cc + h * 64 + quad * 8;
        qf[qq][0] = *(const bf16x8*)(qp);
        qf[qq][1] = *(const bf16x8*)(qp + 32);
    }

    f32x4 oacc[4][4] = {};
    f32x4 lacc[4]    = {};
    const __bf16 onebf = (__bf16)1.0f;
    const bf16x8 ones  = {onebf, onebf, onebf, onebf, onebf, onebf, onebf, onebf};

    const int nfull = L >> 6;
    const int nch   = (L + 63) >> 6;
    const size_t cb0 = (size_t)bh * 32 * 4096;   // chunk stride 4096 u16
    u16* Pw = Pss[w];

    // ---- prologue: chunk 0 -> regs -> LDS ----
    {
        uint4 k0a = *(const uint4*)&kx[cb0 + t * 8];
        uint4 k0b = *(const uint4*)&kx[cb0 + 2048 + t * 8];
        uint4 v0a = *(const uint4*)&vx[cb0 + t * 8];
        uint4 v0b = *(const uint4*)&vx[cb0 + 2048 + t * 8];
        *(uint4*)&KVs[t * 8]        = k0a;
        *(uint4*)&KVs[2048 + t * 8] = k0b;
        *(uint4*)&KVs[4096 + t * 8] = v0a;
        *(uint4*)&KVs[6144 + t * 8] = v0b;
    }
    __syncthreads();

    for (int ch = 0; ch < nch; ++ch) {
        // ---- T14: issue next-chunk loads now; first use is after barrier ----
        const int cc = (ch + 1 < nch) ? ch + 1 : ch;
        const size_t nb = cb0 + (size_t)cc * 4096;
        uint4 nk0 = *(const uint4*)&kx[nb + t * 8];
        uint4 nk1 = *(const uint4*)&kx[nb + 2048 + t * 8];
        uint4 nv0 = *(const uint4*)&vx[nb + t * 8];
        uint4 nv1 = *(const uint4*)&vx[nb + 2048 + t * 8];

        const u16* Kb = KVs;
        const u16* Vb = KVs + 4096;

        // ---- K fragments from LDS (linear, conflict-free) ----
        bf16x8 kf[4][2];
        #pragma unroll
        for (int jt = 0; jt < 4; ++jt)
            #pragma unroll
            for (int ks = 0; ks < 2; ++ks)
                kf[jt][ks] = *(const bf16x8*)&Kb[(jt * 2 + ks) * 512 + lane * 8];

        // ---- V fragments ----
        bf16x8 vf[4][2];
        #pragma unroll
        for (int dt = 0; dt < 4; ++dt)
            #pragma unroll
            for (int ks = 0; ks < 2; ++ks)
                vf[dt][ks] = *(const bf16x8*)&Vb[(dt * 2 + ks) * 512 + lane * 8];

        // ---- per q-tile: S, exp, P slab roundtrip, PV ----
        #pragma unroll
        for (int qq = 0; qq < 4; ++qq) {
            f32x4 st[4];
            #pragma unroll
            for (int jt = 0; jt < 4; ++jt) {
                f32x4 z = {0.f, 0.f, 0.f, 0.f};
                z = mfma16(kf[jt][0], qf[qq][0], z);
                st[jt] = mfma16(kf[jt][1], qf[qq][1], z);
            }
            uint2 pk[4];
            if (ch < nfull) {
                #pragma unroll
                for (int jt = 0; jt < 4; ++jt) {
                    pk[jt].x = cvt_pk_bf16(fexp2(st[jt][0]), fexp2(st[jt][1]));
                    pk[jt].y = cvt_pk_bf16(fexp2(st[jt][2]), fexp2(st[jt][3]));
                }
            } else {
                const int kc = ch * 64;
                #pragma unroll
                for (int jt = 0; jt < 4; ++jt) {
                    const int kb = kc + 16 * jt + quad * 4;
                    float e[4];
                    #pragma unroll
                    for (int r = 0; r < 4; ++r)
                        e[r] = (kb + r < L) ? fexp2(st[jt][r]) : 0.f;
                    pk[jt].x = cvt_pk_bf16(e[0], e[1]);
                    pk[jt].y = cvt_pk_bf16(e[2], e[3]);
                }
            }
            #pragma unroll
            for (int jt = 0; jt < 4; ++jt)
                *(uint2*)&Pw[l16 * 68 + 16 * jt + quad * 4] = pk[jt];

            #pragma unroll
            for (int ks = 0; ks < 2; ++ks) {
                const u16* pr = &Pw[l16 * 68 + 32 * ks + quad * 8];
                uint2 pa = *(const uint2*)pr;
                uint2 pb = *(const uint2*)(pr + 4);
                uint4 comb = {pa.x, pa.y, pb.x, pb.y};
                bf16x8 pf = *(const bf16x8*)&comb;
                #pragma unroll
                for (int dt = 0; dt < 4; ++dt)
                    oacc[qq][dt] = mfma16(pf, vf[dt][ks], oacc[qq][dt]);
                lacc[qq] = mfma16(pf, ones, lacc[qq]);
            }
        }

        // ---- rotate buffer: all readers done -> write next chunk ----
        __syncthreads();
        *(uint4*)&KVs[t * 8]        = nk0;
        *(uint4*)&KVs[2048 + t * 8] = nk1;
        *(uint4*)&KVs[4096 + t * 8] = nv0;
        *(uint4*)&KVs[6144 + t * 8] = nv1;
        __syncthreads();
    }

    // ---- write O (bf16, [B*T, C]) ----
    #pragma unroll
    for (int qq = 0; qq < 4; ++qq)
        #pragma unroll
        for (int r = 0; r < 4; ++r) {
            const float inv = 1.f / lacc[qq][r];
            const size_t ro = (size_t)(b * Tt + q0 + 16 * qq + quad * 4 + r) * Cc + h * 64 + l16;
            #pragma unroll
            for (int dt = 0; dt < 4; ++dt)
                outO[ro + 16 * dt] = f2bf_hw(oacc[qq][dt][r] * inv);
        }
}

// ---------------------------------------------------------------------------
extern "C" void kernel_launch(void* const* d_in, const int* in_sizes, int n_in,
                              void* d_out, int out_size, void* d_ws, size_t ws_size,
                              hipStream_t stream) {
    const float* x     = (const float*)d_in[0];
    const int*   mask  = (const int*)  d_in[1];
    const float* w_qkv = (const float*)d_in[2];
    const float* w_out = (const float*)d_in[3];
    const float* b_out = (const float*)d_in[4];
    float*       outp  = (float*)d_out;

    const int M = Bb * Tt;                        // 8192
    char* ws = (char*)d_ws;
    u16* xb     = (u16*)(ws);                     // 16 MB  [M,C]  (dead after gemm1)
    u16* wqkvT  = (u16*)(ws + (16u << 20));       //  6 MB  [3C,C]
    u16* woutT  = (u16*)(ws + (22u << 20));       //  2 MB  [C,C]
    u16* qbuf   = (u16*)(ws + (24u << 20));       // 16 MB  compact Q [M,C]
    u16* kx     = (u16*)(ws + (40u << 20));       // 16 MB  frag-packed K
    u16* vx     = (u16*)(ws + (56u << 20));       // 16 MB  frag-packed V^T
    u16* attnO  = (u16*)(ws);                     // 16 MB  reuses xb region

    const float c2 = 0.18033688011112042f;        // 0.125 * log2(e), folded into Q weights

    cast_f32_bf16<<<(M * Cc / 4 + 255) / 256, 256, 0, stream>>>(x, xb, M * Cc / 4);
    castT_f32_bf16<<<dim3(3 * Cc / 64, Cc / 64), 256, 0, stream>>>(w_qkv, wqkvT, Cc, 3 * Cc, Cc, c2);
    castT_f32_bf16<<<dim3(Cc / 64, Cc / 64), 256, 0, stream>>>(w_out, woutT, Cc, Cc, 0, 1.0f);

    // gemm1 with fused repack: writes qbuf + kx + vx directly
    gemm_qkv_bt<<<dim3(3 * Cc / 128, M / 128), 256, 0, stream>>>(
        xb, wqkvT, qbuf, kx, vx);

    // attn: 4-wave blocks, QBLK=64/wave, 256 q-rows/block (round-7 config)
    attn_mfma4<<<dim3(Bb * Hh, Tt / 256), 256, 0, stream>>>(qbuf, kx, vx, mask, attnO);

    gemm_bt_bf16<<<dim3(Cc / 128, M / 128), 256, 0, stream>>>(
        attnO, woutT, b_out, nullptr, outp, M, Cc, Cc);
}

// Round 10
// 241.930 us; speedup vs baseline: 1.1746x; 1.0783x over previous
//
#include <hip/hip_runtime.h>
#include <hip/hip_bf16.h>

// (B,T,C,H) = (4,2048,1024,16), D=64
#define Bb 4
#define Tt 2048
#define Cc 1024
#define Hh 16

typedef unsigned short u16;
typedef __attribute__((ext_vector_type(8))) __bf16 bf16x8;
typedef __attribute__((ext_vector_type(4))) float  f32x4;

__device__ __forceinline__ u16 f2bf_hw(float f) {         // native cvt on gfx950
    __bf16 h = (__bf16)f;
    return *(u16*)&h;
}

// v_cvt_pk_bf16_f32: low16 = bf16(a), high16 = bf16(b)
__device__ __forceinline__ unsigned cvt_pk_bf16(float a, float b) {
    unsigned r;
    asm("v_cvt_pk_bf16_f32 %0, %1, %2" : "=v"(r) : "v"(a), "v"(b));
    return r;
}

__device__ __forceinline__ float fexp2(float x) {
#if __has_builtin(__builtin_amdgcn_exp2f)
    return __builtin_amdgcn_exp2f(x);
#else
    return __expf(x * 0.6931471805599453f);
#endif
}

__device__ __forceinline__ void gld_lds16(const void* g, void* l) {
    __builtin_amdgcn_global_load_lds(
        (__attribute__((address_space(1))) void*)(g),
        (__attribute__((address_space(3))) void*)(l),
        16, 0, 0);
}

__device__ __forceinline__ f32x4 mfma16(bf16x8 a, bf16x8 b, f32x4 c) {
    return __builtin_amdgcn_mfma_f32_16x16x32_bf16(a, b, c, 0, 0, 0);
}

// ---------------------------------------------------------------------------
__global__ void cast_f32_bf16(const float* __restrict__ in, u16* __restrict__ out, int n4) {
    int i = blockIdx.x * 256 + threadIdx.x;
    if (i < n4) {
        float4 v = ((const float4*)in)[i];
        uint2 o;
        o.x = cvt_pk_bf16(v.x, v.y);
        o.y = cvt_pk_bf16(v.z, v.w);
        ((uint2*)out)[i] = o;
    }
}

// cast + transpose: in [K,N] f32 -> out [N,K] bf16, rows n < scaleN scaled by sv.
__global__ void castT_f32_bf16(const float* __restrict__ in, u16* __restrict__ out,
                               int K, int N, int scaleN, float sv) {
    __shared__ float Ls[64][65];
    const int n0 = blockIdx.x * 64, k0 = blockIdx.y * 64;
    const int t = threadIdx.x;
    #pragma unroll
    for (int s = 0; s < 4; ++s) {
        int idx = t + 256 * s;
        int r   = idx >> 4;
        int c4  = (idx & 15) * 4;
        float4 v = *(const float4*)&in[(size_t)(k0 + r) * N + n0 + c4];
        Ls[r][c4 + 0] = v.x; Ls[r][c4 + 1] = v.y;
        Ls[r][c4 + 2] = v.z; Ls[r][c4 + 3] = v.w;
    }
    __syncthreads();
    #pragma unroll
    for (int s = 0; s < 2; ++s) {
        int idx = t + 256 * s;
        int n   = idx >> 3;
        int kc  = (idx & 7) * 8;
        const float sc = (n0 + n < scaleN) ? sv : 1.0f;
        alignas(16) u16 tmp[8];
        #pragma unroll
        for (int i = 0; i < 8; ++i) tmp[i] = f2bf_hw(Ls[kc + i][n] * sc);
        *(uint4*)&out[(size_t)(n0 + n) * K + k0 + kc] = *(const uint4*)tmp;
    }
}

// ---------------------------------------------------------------------------
// bf16 GEMM, B^T input — BK=64 variant of the m97 structure (round 9->10).
// Rationale: the 2-barrier + vmcnt(0) drain happens per K-step; BK 32->64
// halves drain points (32->16 for K=1024) while keeping the 128^2 tile and
// 3-blocks/CU residency that beat the 256^2 kernels here. Staging/read
// addressing lifted verbatim from the refcheck-verified gemm_bt_256 pattern:
// linear LDS dest, source granule g_log = (lane&7)^(row&7) involution,
// fragment read granule (4kk+quad)^(row&7). LDS 32KB -> still 3 blocks/CU.
// ---------------------------------------------------------------------------
__global__ __launch_bounds__(256, 3) void gemm_bt_bf16(
    const u16* __restrict__ A, const u16* __restrict__ Bt,
    const float* __restrict__ bias,
    u16* __restrict__ outB, float* __restrict__ outF,
    int M, int N, int K)
{
    __shared__ u16 As[128 * 64];
    __shared__ u16 Bs[128 * 64];
    const int t = threadIdx.x;
    const int w = t >> 6, lane = t & 63;
    const int quad = lane >> 4, l16 = lane & 15;
    const int wm = w >> 1, wn = w & 1;
    const int m0 = blockIdx.y * 128, n0 = blockIdx.x * 128;

    // staging: wave w, pair u covers rows [(4w+u)*8, +8); row-in-group l8r,
    // source k-granule pre-swizzled so linear LDS slot s holds granule s^(row&7)
    const int l8r   = lane >> 3;
    const int g_log = (lane & 7) ^ l8r;
    const u16* sAp[4]; const u16* sBp[4];
    #pragma unroll
    for (int u = 0; u < 4; ++u) {
        const int gi = w * 4 + u;                     // [0,16)
        sAp[u] = A  + (size_t)(m0 + gi * 8 + l8r) * K + g_log * 8;
        sBp[u] = Bt + (size_t)(n0 + gi * 8 + l8r) * K + g_log * 8;
    }
    const int dst0 = w * 2048 + lane * 8;             // u16 units

    // fragment read offsets: row r, kk-half granule (4kk+quad)^(r&7)
    int aoff[4][2], boff[4][2];
    #pragma unroll
    for (int i = 0; i < 4; ++i) {
        const int rA = 64 * wm + 16 * i + l16;
        const int rB = 64 * wn + 16 * i + l16;
        #pragma unroll
        for (int kk = 0; kk < 2; ++kk) {
            aoff[i][kk] = rA * 64 + (((4 * kk + quad) ^ (rA & 7)) * 8);
            boff[i][kk] = rB * 64 + (((4 * kk + quad) ^ (rB & 7)) * 8);
        }
    }

    f32x4 acc[4][4] = {};

    for (int k0 = 0; k0 < K; k0 += 64) {
        __syncthreads();
        #pragma unroll
        for (int u = 0; u < 4; ++u) {
            gld_lds16(sAp[u] + k0, (void*)(As + dst0 + u * 512));
            gld_lds16(sBp[u] + k0, (void*)(Bs + dst0 + u * 512));
        }
        asm volatile("s_waitcnt vmcnt(0)" ::: "memory");
        __syncthreads();

        #pragma unroll
        for (int kk = 0; kk < 2; ++kk) {
            bf16x8 af[4], bfr[4];
            #pragma unroll
            for (int i = 0; i < 4; ++i) af[i]  = *(const bf16x8*)&As[aoff[i][kk]];
            #pragma unroll
            for (int j = 0; j < 4; ++j) bfr[j] = *(const bf16x8*)&Bs[boff[j][kk]];
            #pragma unroll
            for (int i = 0; i < 4; ++i)
                #pragma unroll
                for (int j = 0; j < 4; ++j)
                    acc[i][j] = mfma16(af[i], bfr[j], acc[i][j]);
        }
    }

    const int rbase = m0 + 64 * wm + quad * 4;
    const int cbase = n0 + 64 * wn + l16;
    if (outF) {
        float bv[4];
        #pragma unroll
        for (int j = 0; j < 4; ++j) bv[j] = bias[cbase + 16 * j];
        #pragma unroll
        for (int i = 0; i < 4; ++i)
            #pragma unroll
            for (int r = 0; r < 4; ++r) {
                size_t ro = (size_t)(rbase + 16 * i + r) * N;
                #pragma unroll
                for (int j = 0; j < 4; ++j)
                    outF[ro + cbase + 16 * j] = acc[i][j][r] + bv[j];
            }
    } else {
        #pragma unroll
        for (int i = 0; i < 4; ++i)
            #pragma unroll
            for (int r = 0; r < 4; ++r) {
                size_t ro = (size_t)(rbase + 16 * i + r) * N;
                #pragma unroll
                for (int j = 0; j < 4; ++j)
                    outB[ro + cbase + 16 * j] = f2bf_hw(acc[i][j][r]);
            }
    }
}

// ---------------------------------------------------------------------------
// gemm1 with FUSED repack (round-9 win, kept) — BK=64 main loop (same as
// gemm_bt_bf16 above), epilogue scatters into qb/kx/vx layouts directly.
// Fragment indices separable: idx = rowpart(row) + colpart(col); verified
// element-wise vs the old repack_frags. Region uniform per block (n0>>10).
// ---------------------------------------------------------------------------
__global__ __launch_bounds__(256, 3) void gemm_qkv_bt(
    const u16* __restrict__ A, const u16* __restrict__ Bt,
    u16* __restrict__ outQ, u16* __restrict__ kx, u16* __restrict__ vx)
{
    const int K = Cc;
    __shared__ u16 As[128 * 64];
    __shared__ u16 Bs[128 * 64];
    const int t = threadIdx.x;
    const int w = t >> 6, lane = t & 63;
    const int quad = lane >> 4, l16 = lane & 15;
    const int wm = w >> 1, wn = w & 1;
    const int m0 = blockIdx.y * 128, n0 = blockIdx.x * 128;

    const int l8r   = lane >> 3;
    const int g_log = (lane & 7) ^ l8r;
    const u16* sAp[4]; const u16* sBp[4];
    #pragma unroll
    for (int u = 0; u < 4; ++u) {
        const int gi = w * 4 + u;
        sAp[u] = A  + (size_t)(m0 + gi * 8 + l8r) * K + g_log * 8;
        sBp[u] = Bt + (size_t)(n0 + gi * 8 + l8r) * K + g_log * 8;
    }
    const int dst0 = w * 2048 + lane * 8;

    int aoff[4][2], boff[4][2];
    #pragma unroll
    for (int i = 0; i < 4; ++i) {
        const int rA = 64 * wm + 16 * i + l16;
        const int rB = 64 * wn + 16 * i + l16;
        #pragma unroll
        for (int kk = 0; kk < 2; ++kk) {
            aoff[i][kk] = rA * 64 + (((4 * kk + quad) ^ (rA & 7)) * 8);
            boff[i][kk] = rB * 64 + (((4 * kk + quad) ^ (rB & 7)) * 8);
        }
    }

    f32x4 acc[4][4] = {};

    for (int k0 = 0; k0 < K; k0 += 64) {
        __syncthreads();
        #pragma unroll
        for (int u = 0; u < 4; ++u) {
            gld_lds16(sAp[u] + k0, (void*)(As + dst0 + u * 512));
            gld_lds16(sBp[u] + k0, (void*)(Bs + dst0 + u * 512));
        }
        asm volatile("s_waitcnt vmcnt(0)" ::: "memory");
        __syncthreads();

        #pragma unroll
        for (int kk = 0; kk < 2; ++kk) {
            bf16x8 af[4], bfr[4];
            #pragma unroll
            for (int i = 0; i < 4; ++i) af[i]  = *(const bf16x8*)&As[aoff[i][kk]];
            #pragma unroll
            for (int j = 0; j < 4; ++j) bfr[j] = *(const bf16x8*)&Bs[boff[j][kk]];
            #pragma unroll
            for (int i = 0; i < 4; ++i)
                #pragma unroll
                for (int j = 0; j < 4; ++j)
                    acc[i][j] = mfma16(af[i], bfr[j], acc[i][j]);
        }
    }

    const int rbase = m0 + 64 * wm + quad * 4;      // + 16*i + r = global row
    const int cbase = n0 + 64 * wn + l16;           // + 16*j    = global col
    const int region = n0 >> 10;                    // 0=Q, 1=K, 2=V (uniform)

    if (region == 0) {
        #pragma unroll
        for (int i = 0; i < 4; ++i)
            #pragma unroll
            for (int r = 0; r < 4; ++r) {
                size_t ro = (size_t)(rbase + 16 * i + r) * Cc;
                #pragma unroll
                for (int j = 0; j < 4; ++j)
                    outQ[ro + cbase + 16 * j] = f2bf_hw(acc[i][j][r]);
            }
    } else if (region == 1) {
        int colK[4];
        #pragma unroll
        for (int j = 0; j < 4; ++j) {
            const int c = (cbase - 1024) + 16 * j;
            const int h = c >> 6, d = c & 63;
            colK[j] = h * 131072 + (d >> 5) * 512 + ((d >> 3) & 3) * 128 + (d & 7);
        }
        #pragma unroll
        for (int i = 0; i < 4; ++i)
            #pragma unroll
            for (int r = 0; r < 4; ++r) {
                const int row = rbase + 16 * i + r;
                const int b = row >> 11, key = row & 2047;
                const int ch = key >> 6, keyr = key & 63;
                const int rowK = b * 2097152 + ch * 4096 + (keyr >> 4) * 1024 + (keyr & 15) * 8;
                #pragma unroll
                for (int j = 0; j < 4; ++j)
                    kx[rowK + colK[j]] = f2bf_hw(acc[i][j][r]);
            }
    } else {
        int colV[4];
        #pragma unroll
        for (int j = 0; j < 4; ++j) {
            const int c = (cbase - 2048) + 16 * j;
            const int h = c >> 6, d = c & 63;
            colV[j] = h * 131072 + (d >> 4) * 1024 + (d & 15) * 8;
        }
        #pragma unroll
        for (int i = 0; i < 4; ++i)
            #pragma unroll
            for (int r = 0; r < 4; ++r) {
                const int row = rbase + 16 * i + r;
                const int b = row >> 11, key = row & 2047;
                const int ch = key >> 6, keyr = key & 63;
                const int rowV = b * 2097152 + ch * 4096 + (keyr >> 5) * 512
                               + ((keyr >> 3) & 3) * 128 + (keyr & 7);
                #pragma unroll
                for (int j = 0; j < 4; ++j)
                    vx[rowV + colV[j]] = f2bf_hw(acc[i][j][r]);
            }
    }
}

// ---------------------------------------------------------------------------
// Flash attention — round-7 structure + T5 s_setprio around MFMA clusters
// (documented +4-7% for attn with independent blocks/CU; null only for
// lockstep GEMM). 4 waves/block, QBLK=64/wave, 512 blocks, single-buffer KV
// + T14 reg prefetch, per-wave 16x68 P slab.
// ---------------------------------------------------------------------------
__global__ __launch_bounds__(256, 2) void attn_mfma4(
    const u16* __restrict__ qb, const u16* __restrict__ kx, const u16* __restrict__ vx,
    const int* __restrict__ mask, u16* __restrict__ outO)
{
    __shared__ u16 KVs[8192];          // K:0..4095 | V:4096..8191  (16KB)
    __shared__ u16 Pss[4][16 * 68];    // per-wave per-qq P slab    (8.5KB)

    const int t = threadIdx.x;
    const int w = t >> 6, lane = t & 63;
    const int quad = lane >> 4, l16 = lane & 15;
    const int bh = blockIdx.x, qblk = blockIdx.y, b = bh >> 4, h = bh & 15;

    // ---- valid length L from prefix mask ----
    int sum = 0;
    {
        const int4* mp = (const int4*)(mask + b * Tt) + lane * 8;
        #pragma unroll
        for (int i = 0; i < 8; ++i) { int4 m4 = mp[i]; sum += m4.x + m4.y + m4.z + m4.w; }
        #pragma unroll
        for (int off = 1; off < 64; off <<= 1) sum += __shfl_xor(sum, off);
    }
    const int L = sum;

    // ---- persistent Q fragments (pre-scaled at weight cast) ----
    const int q0 = qblk * 256 + w * 64;
    bf16x8 qf[4][2];
    #pragma unroll
    for (int qq = 0; qq < 4; ++qq) {
        const u16* qp = qb + (size_t)(b * Tt + q0 + 16 * qq + l16) * Cc + h * 64 + quad * 8;
        qf[qq][0] = *(const bf16x8*)(qp);
        qf[qq][1] = *(const bf16x8*)(qp + 32);
    }

    f32x4 oacc[4][4] = {};
    f32x4 lacc[4]    = {};
    const __bf16 onebf = (__bf16)1.0f;
    const bf16x8 ones  = {onebf, onebf, onebf, onebf, onebf, onebf, onebf, onebf};

    const int nfull = L >> 6;
    const int nch   = (L + 63) >> 6;
    const size_t cb0 = (size_t)bh * 32 * 4096;   // chunk stride 4096 u16
    u16* Pw = Pss[w];

    // ---- prologue: chunk 0 -> regs -> LDS ----
    {
        uint4 k0a = *(const uint4*)&kx[cb0 + t * 8];
        uint4 k0b = *(const uint4*)&kx[cb0 + 2048 + t * 8];
        uint4 v0a = *(const uint4*)&vx[cb0 + t * 8];
        uint4 v0b = *(const uint4*)&vx[cb0 + 2048 + t * 8];
        *(uint4*)&KVs[t * 8]        = k0a;
        *(uint4*)&KVs[2048 + t * 8] = k0b;
        *(uint4*)&KVs[4096 + t * 8] = v0a;
        *(uint4*)&KVs[6144 + t * 8] = v0b;
    }
    __syncthreads();

    for (int ch = 0; ch < nch; ++ch) {
        // ---- T14: issue next-chunk loads now; first use is after barrier ----
        const int cc = (ch + 1 < nch) ? ch + 1 : ch;
        const size_t nb = cb0 + (size_t)cc * 4096;
        uint4 nk0 = *(const uint4*)&kx[nb + t * 8];
        uint4 nk1 = *(const uint4*)&kx[nb + 2048 + t * 8];
        uint4 nv0 = *(const uint4*)&vx[nb + t * 8];
        uint4 nv1 = *(const uint4*)&vx[nb + 2048 + t * 8];

        const u16* Kb = KVs;
        const u16* Vb = KVs + 4096;

        // ---- K fragments from LDS (linear, conflict-free) ----
        bf16x8 kf[4][2];
        #pragma unroll
        for (int jt = 0; jt < 4; ++jt)
            #pragma unroll
            for (int ks = 0; ks < 2; ++ks)
                kf[jt][ks] = *(const bf16x8*)&Kb[(jt * 2 + ks) * 512 + lane * 8];

        // ---- V fragments ----
        bf16x8 vf[4][2];
        #pragma unroll
        for (int dt = 0; dt < 4; ++dt)
            #pragma unroll
            for (int ks = 0; ks < 2; ++ks)
                vf[dt][ks] = *(const bf16x8*)&Vb[(dt * 2 + ks) * 512 + lane * 8];

        // ---- per q-tile: S, exp, P slab roundtrip, PV ----
        #pragma unroll
        for (int qq = 0; qq < 4; ++qq) {
            f32x4 st[4];
            __builtin_amdgcn_s_setprio(1);
            #pragma unroll
            for (int jt = 0; jt < 4; ++jt) {
                f32x4 z = {0.f, 0.f, 0.f, 0.f};
                z = mfma16(kf[jt][0], qf[qq][0], z);
                st[jt] = mfma16(kf[jt][1], qf[qq][1], z);
            }
            __builtin_amdgcn_s_setprio(0);
            uint2 pk[4];
            if (ch < nfull) {
                #pragma unroll
                for (int jt = 0; jt < 4; ++jt) {
                    pk[jt].x = cvt_pk_bf16(fexp2(st[jt][0]), fexp2(st[jt][1]));
                    pk[jt].y = cvt_pk_bf16(fexp2(st[jt][2]), fexp2(st[jt][3]));
                }
            } else {
                const int kc = ch * 64;
                #pragma unroll
                for (int jt = 0; jt < 4; ++jt) {
                    const int kb = kc + 16 * jt + quad * 4;
                    float e[4];
                    #pragma unroll
                    for (int r = 0; r < 4; ++r)
                        e[r] = (kb + r < L) ? fexp2(st[jt][r]) : 0.f;
                    pk[jt].x = cvt_pk_bf16(e[0], e[1]);
                    pk[jt].y = cvt_pk_bf16(e[2], e[3]);
                }
            }
            #pragma unroll
            for (int jt = 0; jt < 4; ++jt)
                *(uint2*)&Pw[l16 * 68 + 16 * jt + quad * 4] = pk[jt];

            __builtin_amdgcn_s_setprio(1);
            #pragma unroll
            for (int ks = 0; ks < 2; ++ks) {
                const u16* pr = &Pw[l16 * 68 + 32 * ks + quad * 8];
                uint2 pa = *(const uint2*)pr;
                uint2 pb = *(const uint2*)(pr + 4);
                uint4 comb = {pa.x, pa.y, pb.x, pb.y};
                bf16x8 pf = *(const bf16x8*)&comb;
                #pragma unroll
                for (int dt = 0; dt < 4; ++dt)
                    oacc[qq][dt] = mfma16(pf, vf[dt][ks], oacc[qq][dt]);
                lacc[qq] = mfma16(pf, ones, lacc[qq]);
            }
            __builtin_amdgcn_s_setprio(0);
        }

        // ---- rotate buffer: all readers done -> write next chunk ----
        __syncthreads();
        *(uint4*)&KVs[t * 8]        = nk0;
        *(uint4*)&KVs[2048 + t * 8] = nk1;
        *(uint4*)&KVs[4096 + t * 8] = nv0;
        *(uint4*)&KVs[6144 + t * 8] = nv1;
        __syncthreads();
    }

    // ---- write O (bf16, [B*T, C]) ----
    #pragma unroll
    for (int qq = 0; qq < 4; ++qq)
        #pragma unroll
        for (int r = 0; r < 4; ++r) {
            const float inv = 1.f / lacc[qq][r];
            const size_t ro = (size_t)(b * Tt + q0 + 16 * qq + quad * 4 + r) * Cc + h * 64 + l16;
            #pragma unroll
            for (int dt = 0; dt < 4; ++dt)
                outO[ro + 16 * dt] = f2bf_hw(oacc[qq][dt][r] * inv);
        }
}

// ---------------------------------------------------------------------------
extern "C" void kernel_launch(void* const* d_in, const int* in_sizes, int n_in,
                              void* d_out, int out_size, void* d_ws, size_t ws_size,
                              hipStream_t stream) {
    const float* x     = (const float*)d_in[0];
    const int*   mask  = (const int*)  d_in[1];
    const float* w_qkv = (const float*)d_in[2];
    const float* w_out = (const float*)d_in[3];
    const float* b_out = (const float*)d_in[4];
    float*       outp  = (float*)d_out;

    const int M = Bb * Tt;                        // 8192
    char* ws = (char*)d_ws;
    u16* xb     = (u16*)(ws);                     // 16 MB  [M,C]  (dead after gemm1)
    u16* wqkvT  = (u16*)(ws + (16u << 20));       //  6 MB  [3C,C]
    u16* woutT  = (u16*)(ws + (22u << 20));       //  2 MB  [C,C]
    u16* qbuf   = (u16*)(ws + (24u << 20));       // 16 MB  compact Q [M,C]
    u16* kx     = (u16*)(ws + (40u << 20));       // 16 MB  frag-packed K
    u16* vx     = (u16*)(ws + (56u << 20));       // 16 MB  frag-packed V^T
    u16* attnO  = (u16*)(ws);                     // 16 MB  reuses xb region

    const float c2 = 0.18033688011112042f;        // 0.125 * log2(e), folded into Q weights

    cast_f32_bf16<<<(M * Cc / 4 + 255) / 256, 256, 0, stream>>>(x, xb, M * Cc / 4);
    castT_f32_bf16<<<dim3(3 * Cc / 64, Cc / 64), 256, 0, stream>>>(w_qkv, wqkvT, Cc, 3 * Cc, Cc, c2);
    castT_f32_bf16<<<dim3(Cc / 64, Cc / 64), 256, 0, stream>>>(w_out, woutT, Cc, Cc, 0, 1.0f);

    // gemm1 with fused repack (BK=64): writes qbuf + kx + vx directly
    gemm_qkv_bt<<<dim3(3 * Cc / 128, M / 128), 256, 0, stream>>>(
        xb, wqkvT, qbuf, kx, vx);

    // attn: 4-wave blocks, QBLK=64/wave, 256 q-rows/block (+ setprio)
    attn_mfma4<<<dim3(Bb * Hh, Tt / 256), 256, 0, stream>>>(qbuf, kx, vx, mask, attnO);

    gemm_bt_bf16<<<dim3(Cc / 128, M / 128), 256, 0, stream>>>(
        attnO, woutT, b_out, nullptr, outp, M, Cc, Cc);
}